// Round 2
// baseline (492.052 us; speedup 1.0000x reference)
//
#include <hip/hip_runtime.h>
#include <hip/hip_bf16.h>

#define NT 4           // node types (labels)
#define FEAT 256       // nfeat == nhid
#define OUT3 64        // nclass

typedef __bf16 bf16x8 __attribute__((ext_vector_type(8)));
typedef float  f32x4  __attribute__((ext_vector_type(4)));
typedef unsigned int u32x2 __attribute__((ext_vector_type(2)));

__device__ inline unsigned int f2bf_bits(float f) {
    __hip_bfloat16 h = __float2bfloat16(f);   // RNE
    unsigned short u;
    __builtin_memcpy(&u, &h, 2);
    return (unsigned int)u;
}
__device__ inline float bfl(unsigned int u) { return __uint_as_float(u << 16); }
__device__ inline float bfh(unsigned int u) { return __uint_as_float(u & 0xffff0000u); }
// stored feature pos p (pi order) -> natural feature index, within each 64-block
__device__ __host__ inline int nat_of(int p) {
    int lo = p & 63;
    return (p & ~63) | (((lo & 3) << 4) | (lo >> 2));
}

// ---------------- pass A: dst-bucket histogram (dst>>8) + label histogram ----------------
__global__ __launch_bounds__(512) void pass_a(const int* __restrict__ dst,
                                              const int* __restrict__ labels,
                                              int* __restrict__ bcnt, int* __restrict__ lc,
                                              int E, int N) {
    __shared__ int h[256];
    __shared__ int lh[NT];
    int tid = threadIdx.x;
    if (tid < 256) h[tid] = 0;
    if (tid < NT) lh[tid] = 0;
    __syncthreads();
    int base = blockIdx.x * 4096;
#pragma unroll
    for (int k = 0; k < 8; ++k) {
        int e = base + k * 512 + tid;
        if (e < E) atomicAdd(&h[((unsigned)dst[e]) >> 8], 1);
    }
#pragma unroll
    for (int k = 0; k < 8; ++k) {
        int i = base + k * 512 + tid;
        if (i < N) atomicAdd(&lh[labels[i]], 1);
    }
    __syncthreads();
    if (tid < 256) { int v = h[tid]; if (v) atomicAdd(&bcnt[tid], v); }
    if (tid < NT) { int v = lh[tid]; if (v) atomicAdd(&lc[tid], v); }
}

// ------- scan buckets -> boff/gcur, rowoff[N]=E; label starts (pad 64) -------
__global__ __launch_bounds__(256) void scan_master(
    const int* __restrict__ bcnt, const int* __restrict__ lc,
    int* __restrict__ boff, int* __restrict__ gcur, int* __restrict__ rowoff,
    int* __restrict__ lstart, int NB, int N, int E) {
    __shared__ int s[256];
    int tid = threadIdx.x;
    int own = (tid < NB) ? bcnt[tid] : 0;
    s[tid] = own;
    __syncthreads();
    for (int d = 1; d < 256; d <<= 1) {
        int v = (tid >= d) ? s[tid - d] : 0;
        __syncthreads();
        s[tid] += v;
        __syncthreads();
    }
    int excl = s[tid] - own;
    if (tid < NB) { boff[tid] = excl; gcur[tid] = excl; }
    if (tid == 0) {
        boff[NB] = E; rowoff[N] = E;
        int run = 0;
        for (int l = 0; l < NT; ++l) {
            lstart[l] = run;
            run += (lc[l] + 63) & ~63;
        }
    }
}

// ------- node scatter: build iperm (orig -> label-sorted slot) -------
__global__ void scatter_nodes(const int* __restrict__ labels, const int* __restrict__ lstart,
                              int* __restrict__ lcur, int* __restrict__ iperm, int N) {
    int n = blockIdx.x * 256 + threadIdx.x;
    int lab = (n < N) ? labels[n] : -1;
    int lane = threadIdx.x & 63;
    for (int l = 0; l < NT; ++l) {
        unsigned long long m = __ballot(lab == l);
        if (m == 0ull) continue;
        int leader = __builtin_ctzll(m);
        int base = 0;
        if (lane == leader) base = atomicAdd(&lcur[l], (int)__popcll(m));
        base = __shfl(base, leader, 64);
        if (lab == l) {
            int prefix = (int)__popcll(m & ((1ull << lane) - 1ull));
            iperm[n] = lstart[l] + base + prefix;
        }
    }
}

// ================= FUSE_A: scatter_edges + cast_x + cast_w_all =================
// seg 0 [0, nbEB): edge scatter into bucket regions; earr rec: x = slot|(dst&255)<<16, y = w
// seg 1 [nbEB, nbEB+nbX): cast x -> bf16 full 256-feat slot rows
// seg 2 rest: cast W1/W2/W3 -> swizzled bf16 + permuted biases
__global__ __launch_bounds__(512) void fuse_a(
    const int* __restrict__ src, const int* __restrict__ dst, const float* __restrict__ w,
    const int* __restrict__ iperm, int* __restrict__ gcur, uint2* __restrict__ earr, int E,
    const float* __restrict__ x, unsigned short* __restrict__ act, int total4,
    const float* __restrict__ W1, const float* __restrict__ W2, const float* __restrict__ W3,
    const float* __restrict__ b1, const float* __restrict__ b2,
    unsigned short* __restrict__ W1b, unsigned short* __restrict__ W2b,
    unsigned short* __restrict__ W3b, float* __restrict__ biasPerm,
    int nbEB, int nbX) {
    int tid = threadIdx.x;
    int blk = (int)blockIdx.x;
    if (blk < nbEB) {
        // ---- edge scatter ----
        __shared__ int h[256];
        __shared__ int basearr[256];
        if (tid < 256) h[tid] = 0;
        __syncthreads();
        int base = blk * 4096;
        int b[8], rank[8], px[8]; float wv[8];
#pragma unroll
        for (int k = 0; k < 8; ++k) {
            int e = base + k * 512 + tid;
            if (e < E) {
                int d = dst[e];
                b[k] = ((unsigned)d) >> 8;
                px[k] = iperm[src[e]] | ((d & 255) << 16);
                wv[k] = w[e];
                rank[k] = atomicAdd(&h[b[k]], 1);
            } else b[k] = -1;
        }
        __syncthreads();
        if (tid < 256) { int c = h[tid]; basearr[tid] = c ? atomicAdd(&gcur[tid], c) : 0; }
        __syncthreads();
#pragma unroll
        for (int k = 0; k < 8; ++k) {
            if (b[k] >= 0) {
                int pos = basearr[b[k]] + rank[k];
                earr[pos] = make_uint2((unsigned)px[k], __float_as_uint(wv[k]));
            }
        }
    } else if (blk < nbEB + nbX) {
        // ---- cast x: full row, uint2 idx = i&63 covers natural feats 4i..4i+3 ----
        int i = (blk - nbEB) * 512 + tid;
        if (i < total4) {
            float4 v = ((const float4*)x)[i];
            unsigned int lo = f2bf_bits(v.x) | (f2bf_bits(v.y) << 16);
            unsigned int hi = f2bf_bits(v.z) | (f2bf_bits(v.w) << 16);
            int slot = iperm[i >> 6];
            ((uint2*)act)[(size_t)slot * 64 + (i & 63)] = make_uint2(lo, hi);
        }
    } else {
        // ---- cast W + biases ----
        const int S = NT * FEAT * FEAT;
        const int S3 = NT * FEAT * OUT3;
        int idx = (blk - nbEB - nbX) * 512 + tid;
        if (idx < 2 * S + S3) {
            const float* W; unsigned short* D; int OUTF; int t; bool remap;
            if (idx < S)          { W = W1; D = W1b; OUTF = FEAT; t = idx;         remap = false; }
            else if (idx < 2 * S) { W = W2; D = W2b; OUTF = FEAT; t = idx - S;     remap = true; }
            else                  { W = W3; D = W3b; OUTF = OUT3; t = idx - 2 * S; remap = true; }
            int n = t % OUTF;
            int r = t / OUTF;              // lab*256 + k_slot
            int j = r & 7, q = (r >> 3) & 3, k0 = (r >> 5) & 7, lab = r >> 8;
            int k_slot = k0 * 32 + q * 8 + j;
            int k_src = remap ? nat_of(k_slot) : k_slot;
            float f = W[((size_t)(lab * FEAT + k_src)) * OUTF + n];
            D[(((size_t)lab * 8 + k0) * OUTF + n) * 32 + q * 8 + j] = (unsigned short)f2bf_bits(f);
        } else {
            int p2 = idx - (2 * S + S3);
            if (p2 < 256) biasPerm[p2] = b1[nat_of(p2)];
            else if (p2 < 512) biasPerm[p2] = b2[nat_of(p2 - 256)];
        }
    }
}

// ------- bucket sort body (256 thr): within-bucket counting sort -> rowoff + edata -------
// final record: (w_bf16 << 16) | src_slot
__device__ void bucket_sort_body(int b, const uint2* __restrict__ earr,
                                 const int* __restrict__ boff, int* __restrict__ rowoff,
                                 unsigned int* __restrict__ edata, int N) {
    int s = boff[b], e = boff[b + 1];
    __shared__ int cnt[256], off[256];
    int tid = threadIdx.x;
    cnt[tid] = 0;
    __syncthreads();
    for (int i = s + tid; i < e; i += 256) atomicAdd(&cnt[(earr[i].x >> 16) & 255], 1);
    __syncthreads();
    off[tid] = cnt[tid];
    __syncthreads();
    for (int d = 1; d < 256; d <<= 1) {
        int v = (tid >= d) ? off[tid - d] : 0;
        __syncthreads();
        off[tid] += v;
        __syncthreads();
    }
    int excl = off[tid] - cnt[tid];
    int node = b * 256 + tid;
    if (node < N) rowoff[node] = s + excl;
    off[tid] = excl;
    __syncthreads();
    for (int i = s + tid; i < e; i += 256) {
        uint2 r = earr[i];
        int d = (r.x >> 16) & 255;
        int k = atomicAdd(&off[d], 1);
        edata[s + k] = (f2bf_bits(__uint_as_float(r.y)) << 16) | (r.x & 0xffff);
    }
}

// ------- proj 256-out body: dense 64 slots x 256 outs per block, full-row I/O -------
__device__ void proj256_body(int gb,
                             const unsigned short* __restrict__ act,
                             const unsigned short* __restrict__ Wswz,
                             const int* __restrict__ lstart,
                             unsigned short* __restrict__ sup) {
    int warp = threadIdx.x >> 6;
    int lane = threadIdx.x & 63;
    int m0 = gb * 64;
    int lab = (m0 >= lstart[1]) + (m0 >= lstart[2]) + (m0 >= lstart[3]);
    int q = lane >> 4, c = lane & 15;
    int n0 = warp * 64;

    const unsigned short* arow = act + (size_t)(m0 + c) * 256 + q * 8;
    const unsigned short* bb = Wswz + (size_t)lab * FEAT * 256 + (size_t)(n0 + c) * 32 + q * 8;

    f32x4 acc[4][4] = {};
#pragma unroll
    for (int k0 = 0; k0 < 8; ++k0) {
        const unsigned short* abase = arow + ((k0 & 3) * 32) + ((k0 < 4) ? 0 : 128);
        bf16x8 a[4];
#pragma unroll
        for (int t = 0; t < 4; ++t) a[t] = *(const bf16x8*)(abase + (size_t)t * 4096);
        const unsigned short* bk = bb + (size_t)k0 * 32 * 256;
#pragma unroll
        for (int u = 0; u < 4; ++u) {
            bf16x8 bfrag = *(const bf16x8*)(bk + u * 512);
#pragma unroll
            for (int t = 0; t < 4; ++t)
                acc[t][u] = __builtin_amdgcn_mfma_f32_16x16x32_bf16(a[t], bfrag, acc[t][u], 0, 0, 0);
        }
    }
    // pi-store: row = m0+t*16+q*4+r ; lane writes pos p = n0 + c*4 + u -> uint2 idx n0/4 + c
    uint2* ov = (uint2*)sup;
    int cix = (n0 >> 2) + c;
#pragma unroll
    for (int t = 0; t < 4; ++t) {
#pragma unroll
        for (int r = 0; r < 4; ++r) {
            int row = m0 + t * 16 + q * 4 + r;
            unsigned int lo = f2bf_bits(acc[t][0][r]) | (f2bf_bits(acc[t][1][r]) << 16);
            unsigned int hi = f2bf_bits(acc[t][2][r]) | (f2bf_bits(acc[t][3][r]) << 16);
            ov[(size_t)row * 64 + cix] = make_uint2(lo, hi);
        }
    }
}

// ================= FUSE_B: bucket_sort (blocks [0,NB)) + proj256 L1 (rest) =================
__global__ __launch_bounds__(256) void fuse_b(
    const uint2* __restrict__ earr, const int* __restrict__ boff,
    int* __restrict__ rowoff, unsigned int* __restrict__ edata, int N, int NB,
    const unsigned short* __restrict__ act,
    const unsigned short* __restrict__ Wswz, const int* __restrict__ lstart,
    unsigned short* __restrict__ sup) {
    int blk = (int)blockIdx.x;
    if (blk < NB) bucket_sort_body(blk, earr, boff, rowoff, edata, N);
    else proj256_body(blk - NB, act, Wswz, lstart, sup);
}

// ---------------- standalone proj 256 (layer 2) ----------------
__global__ __launch_bounds__(256) void proj256_kernel(
    const unsigned short* __restrict__ act,
    const unsigned short* __restrict__ Wswz, const int* __restrict__ lstart,
    unsigned short* __restrict__ sup) {
    proj256_body((int)blockIdx.x, act, Wswz, lstart, sup);
}

// ---------------- proj 64-out: dense 64 slots x 64 outs per block, full-row input ------
__global__ __launch_bounds__(256) void proj64_kernel(
    const unsigned short* __restrict__ act,
    const unsigned short* __restrict__ Wswz, const int* __restrict__ lstart,
    unsigned short* __restrict__ outp) {
    int warp = threadIdx.x >> 6;
    int lane = threadIdx.x & 63;
    int m0 = blockIdx.x * 64;
    int lab = (m0 >= lstart[1]) + (m0 >= lstart[2]) + (m0 >= lstart[3]);
    int q = lane >> 4, c = lane & 15;
    int mb = m0 + warp * 16;

    const unsigned short* arow = act + (size_t)(mb + c) * 256 + q * 8;
    const unsigned short* bb = Wswz + (size_t)lab * FEAT * OUT3 + (size_t)c * 32 + q * 8;

    f32x4 acc[4] = {};
#pragma unroll
    for (int k0 = 0; k0 < 8; ++k0) {
        bf16x8 a = *(const bf16x8*)(arow + ((k0 & 3) * 32) + ((k0 < 4) ? 0 : 128));
        const unsigned short* bk = bb + (size_t)k0 * 32 * OUT3;
#pragma unroll
        for (int u = 0; u < 4; ++u) {
            bf16x8 bfrag = *(const bf16x8*)(bk + u * 512);
            acc[u] = __builtin_amdgcn_mfma_f32_16x16x32_bf16(a, bfrag, acc[u], 0, 0, 0);
        }
    }
    uint2* ov = (uint2*)outp;
#pragma unroll
    for (int r = 0; r < 4; ++r) {
        int row = mb + q * 4 + r;
        unsigned int lo = f2bf_bits(acc[0][r]) | (f2bf_bits(acc[1][r]) << 16);
        unsigned int hi = f2bf_bits(acc[2][r]) | (f2bf_bits(acc[3][r]) << 16);
        ov[(size_t)row * 16 + c] = make_uint2(lo, hi);
    }
}

// ------- aggregation, FULL 256 feats: one wave per node, uint2 (8B) gathers, unroll 8 ----
// sup row = 64 uint2 (512B). lane handles stored pos p = 4*lane .. 4*lane+3.
// Same per-position accumulation order as the old half-split version (bit-identical sums).
__global__ __launch_bounds__(256) void agg256_kernel(
    const uint2* __restrict__ sup, const int* __restrict__ rowoff,
    const unsigned int* __restrict__ edata, const int* __restrict__ iperm,
    const float* __restrict__ bias, u32x2* __restrict__ outp, int N) {
    int warp = __builtin_amdgcn_readfirstlane((int)(threadIdx.x >> 6));
    int node = (int)blockIdx.x * 4 + warp;
    if (node >= N) return;
    int lane = threadIdx.x & 63;
    int s = __builtin_amdgcn_readfirstlane(rowoff[node]);
    int e = __builtin_amdgcn_readfirstlane(rowoff[node + 1]);
    int slot = __builtin_amdgcn_readfirstlane(iperm[node]);
    float a0 = 0.f, a1 = 0.f, a2 = 0.f, a3 = 0.f;
    int j = s;
    for (; j + 8 <= e; j += 8) {
        unsigned int ed[8]; uint2 v[8];
#pragma unroll
        for (int u = 0; u < 8; ++u) ed[u] = edata[j + u];
#pragma unroll
        for (int u = 0; u < 8; ++u) v[u] = sup[(size_t)(ed[u] & 0xffff) * 64 + lane];
#pragma unroll
        for (int u = 0; u < 8; ++u) {
            float w = __uint_as_float(ed[u] & 0xffff0000u);
            a0 += w * bfl(v[u].x); a1 += w * bfh(v[u].x);
            a2 += w * bfl(v[u].y); a3 += w * bfh(v[u].y);
        }
    }
    if (j < e) {   // masked tail (<=7 real edges)
        unsigned int ed[8]; uint2 v[8]; float wm[8];
#pragma unroll
        for (int u = 0; u < 8; ++u) {
            int jj = j + u;
            int jc = (jj < e) ? jj : e - 1;
            ed[u] = edata[jc];
            wm[u] = (jj < e) ? __uint_as_float(ed[u] & 0xffff0000u) : 0.f;
        }
#pragma unroll
        for (int u = 0; u < 8; ++u) v[u] = sup[(size_t)(ed[u] & 0xffff) * 64 + lane];
#pragma unroll
        for (int u = 0; u < 8; ++u) {
            a0 += wm[u] * bfl(v[u].x); a1 += wm[u] * bfh(v[u].x);
            a2 += wm[u] * bfl(v[u].y); a3 += wm[u] * bfh(v[u].y);
        }
    }
    float4 b = ((const float4*)bias)[lane];
    a0 = fmaxf(a0 + b.x, 0.f);
    a1 = fmaxf(a1 + b.y, 0.f);
    a2 = fmaxf(a2 + b.z, 0.f);
    a3 = fmaxf(a3 + b.w, 0.f);
    u32x2 o;
    o[0] = f2bf_bits(a0) | (f2bf_bits(a1) << 16);
    o[1] = f2bf_bits(a2) | (f2bf_bits(a3) << 16);
    // act rows are not re-read in this kernel: nontemporal store keeps sup lines in L2
    __builtin_nontemporal_store(o, &outp[(size_t)slot * 64 + lane]);
}

// ---------------- aggregation, 64-feat: one wave per node (lane = stored pos), fp32 out --
__global__ __launch_bounds__(256) void agg64_kernel(
    const unsigned short* __restrict__ sup, const int* __restrict__ rowoff,
    const unsigned int* __restrict__ edata, const float* __restrict__ b3,
    float* __restrict__ outp, int N) {
    int warp = __builtin_amdgcn_readfirstlane((int)(threadIdx.x >> 6));
    int node = (int)blockIdx.x * 4 + warp;
    if (node >= N) return;
    int lane = threadIdx.x & 63;
    int s = __builtin_amdgcn_readfirstlane(rowoff[node]);
    int e = __builtin_amdgcn_readfirstlane(rowoff[node + 1]);
    float a = 0.f;
    int j = s;
    for (; j + 8 <= e; j += 8) {
        unsigned int ed[8]; unsigned short v[8];
#pragma unroll
        for (int u = 0; u < 8; ++u) ed[u] = edata[j + u];
#pragma unroll
        for (int u = 0; u < 8; ++u) v[u] = sup[(size_t)(ed[u] & 0xffff) * 64 + lane];
#pragma unroll
        for (int u = 0; u < 8; ++u)
            a += __uint_as_float(ed[u] & 0xffff0000u) * __uint_as_float((unsigned int)v[u] << 16);
    }
    if (j < e) {
        unsigned int ed[8]; float wm[8]; unsigned short v[8];
#pragma unroll
        for (int u = 0; u < 8; ++u) {
            int jj = j + u;
            int jc = (jj < e) ? jj : e - 1;
            ed[u] = edata[jc];
            wm[u] = (jj < e) ? __uint_as_float(ed[u] & 0xffff0000u) : 0.f;
        }
#pragma unroll
        for (int u = 0; u < 8; ++u) v[u] = sup[(size_t)(ed[u] & 0xffff) * 64 + lane];
#pragma unroll
        for (int u = 0; u < 8; ++u)
            a += wm[u] * __uint_as_float((unsigned int)v[u] << 16);
    }
    int natp = (((lane & 3) << 4) | (lane >> 2));    // un-permute pi within the 64 outs
    outp[(size_t)node * 64 + natp] = a + b3[natp];
}

extern "C" void kernel_launch(void* const* d_in, const int* in_sizes, int n_in,
                              void* d_out, int out_size, void* d_ws, size_t ws_size,
                              hipStream_t stream) {
    const float* x        = (const float*)d_in[0];
    const int*   edge_src = (const int*)d_in[1];
    const int*   edge_dst = (const int*)d_in[2];
    const float* edge_w   = (const float*)d_in[3];
    const int*   labels   = (const int*)d_in[4];
    const float* W1 = (const float*)d_in[5];
    const float* b1 = (const float*)d_in[6];
    const float* W2 = (const float*)d_in[7];
    const float* b2 = (const float*)d_in[8];
    const float* W3 = (const float*)d_in[9];
    const float* b3 = (const float*)d_in[10];

    const int N = in_sizes[0] / FEAT;
    const int E = in_sizes[1];
    const int NB = (N + 255) >> 8;                    // dst buckets (orig id space)
    const int G64 = (N + NT * 64 + 63) / 64;          // slot-space 64-row tiles (upper bound)
    const int slotCap = G64 * 64;

    // ---- workspace carve (256B aligned) ----
    char* p = (char*)d_ws;
    auto alloc = [&](size_t bytes) -> char* {
        char* r = p;
        p += (bytes + 255) & ~(size_t)255;
        return r;
    };
    unsigned short* bufA = (unsigned short*)alloc((size_t)slotCap * FEAT * 2);
    unsigned short* bufB = (unsigned short*)alloc((size_t)slotCap * FEAT * 2);
    unsigned short* W1b  = (unsigned short*)alloc((size_t)NT * FEAT * FEAT * 2);
    unsigned short* W2b  = (unsigned short*)alloc((size_t)NT * FEAT * FEAT * 2);
    unsigned short* W3b  = (unsigned short*)alloc((size_t)NT * FEAT * OUT3 * 2);
    float*        biasPerm = (float*)alloc(512 * 4);
    int*          rowoff = (int*)alloc((size_t)(N + 1) * 4);
    unsigned int* edata  = (unsigned int*)alloc((size_t)E * 4);
    int*          iperm  = (int*)alloc((size_t)N * 4);
    int*          counters = (int*)alloc(264 * 4);    // bcnt[256] + lc[4] + lcur[4]
    int*          boff   = (int*)alloc(257 * 4);
    int*          gcur   = (int*)alloc(256 * 4);
    int*          lstart = (int*)alloc(64);
    int* bcnt = counters;
    int* lc   = counters + 256;
    int* lcur = counters + 260;

    // full-row bf16 tables: act (layer input), sup (projection output)
    unsigned short* act = bufA;
    unsigned short* sup = bufB;
    // bucket-sort staging ALIASED onto d_out (N*OUT3*4 = 12.8MB = E*8; d_out written
    // only by the final agg64, and earr is fully overwritten by scatter before reads)
    uint2* earr = (uint2*)d_out;

    const int nbEB = (E + 4095) / 4096;
    const int total4 = N * 64;                        // float4 groups in x
    const int nbX = (total4 + 511) / 512;
    const int totW = 2 * NT * FEAT * FEAT + NT * FEAT * OUT3 + 512;
    const int nbW = (totW + 511) / 512;

    // ---- CSR build + label-sort + casts ----
    hipMemsetAsync(counters, 0, 264 * 4, stream);
    pass_a<<<nbEB, 512, 0, stream>>>(edge_dst, labels, bcnt, lc, E, N);
    scan_master<<<1, 256, 0, stream>>>(bcnt, lc, boff, gcur, rowoff, lstart, NB, N, E);
    scatter_nodes<<<(N + 255) / 256, 256, 0, stream>>>(labels, lstart, lcur, iperm, N);
    fuse_a<<<nbEB + nbX + nbW, 512, 0, stream>>>(
        edge_src, edge_dst, edge_w, iperm, gcur, earr, E,
        x, act, total4,
        W1, W2, W3, b1, b2, W1b, W2b, W3b, biasPerm, nbEB, nbX);

    const int aggGrid = (N + 3) / 4;
    // ---- layer 1 (bucket_sort overlapped with proj256-L1) ----
    fuse_b<<<NB + G64, 256, 0, stream>>>(earr, boff, rowoff, edata, N, NB,
                                         act, W1b, lstart, sup);
    agg256_kernel<<<aggGrid, 256, 0, stream>>>((const uint2*)sup, rowoff, edata, iperm,
                                               biasPerm + 0, (u32x2*)act, N);
    // ---- layer 2 ----
    proj256_kernel<<<G64, 256, 0, stream>>>(act, W2b, lstart, sup);
    agg256_kernel<<<aggGrid, 256, 0, stream>>>((const uint2*)sup, rowoff, edata, iperm,
                                               biasPerm + 256, (u32x2*)act, N);
    // ---- layer 3 ----
    proj64_kernel<<<G64, 256, 0, stream>>>(act, W3b, lstart, bufB);
    agg64_kernel<<<aggGrid, 256, 0, stream>>>(bufB, rowoff, edata, b3, (float*)d_out, N);
}

// Round 3
// 482.177 us; speedup vs baseline: 1.0205x; 1.0205x over previous
//
#include <hip/hip_runtime.h>
#include <hip/hip_bf16.h>

#define NT 4           // node types (labels)
#define FEAT 256       // nfeat == nhid
#define OUT3 64        // nclass

typedef __bf16 bf16x8 __attribute__((ext_vector_type(8)));
typedef float  f32x4  __attribute__((ext_vector_type(4)));

__device__ inline unsigned int f2bf_bits(float f) {
    __hip_bfloat16 h = __float2bfloat16(f);   // RNE
    unsigned short u;
    __builtin_memcpy(&u, &h, 2);
    return (unsigned int)u;
}
__device__ inline float bfl(unsigned int u) { return __uint_as_float(u << 16); }
__device__ inline float bfh(unsigned int u) { return __uint_as_float(u & 0xffff0000u); }
// stored feature pos p (pi order) -> natural feature index, within each 64-block
__device__ __host__ inline int nat_of(int p) {
    int lo = p & 63;
    return (p & ~63) | (((lo & 3) << 4) | (lo >> 2));
}

// ---------------- pass A: dst-bucket histogram (dst>>8) + label histogram ----------------
__global__ __launch_bounds__(512) void pass_a(const int* __restrict__ dst,
                                              const int* __restrict__ labels,
                                              int* __restrict__ bcnt, int* __restrict__ lc,
                                              int E, int N) {
    __shared__ int h[256];
    __shared__ int lh[NT];
    int tid = threadIdx.x;
    if (tid < 256) h[tid] = 0;
    if (tid < NT) lh[tid] = 0;
    __syncthreads();
    int base = blockIdx.x * 4096;
#pragma unroll
    for (int k = 0; k < 8; ++k) {
        int e = base + k * 512 + tid;
        if (e < E) atomicAdd(&h[((unsigned)dst[e]) >> 8], 1);
    }
#pragma unroll
    for (int k = 0; k < 8; ++k) {
        int i = base + k * 512 + tid;
        if (i < N) atomicAdd(&lh[labels[i]], 1);
    }
    __syncthreads();
    if (tid < 256) { int v = h[tid]; if (v) atomicAdd(&bcnt[tid], v); }
    if (tid < NT) { int v = lh[tid]; if (v) atomicAdd(&lc[tid], v); }
}

// ------- scan buckets -> boff/gcur, rowoff[N]=E; label starts (pad 64) -------
__global__ __launch_bounds__(256) void scan_master(
    const int* __restrict__ bcnt, const int* __restrict__ lc,
    int* __restrict__ boff, int* __restrict__ gcur, int* __restrict__ rowoff,
    int* __restrict__ lstart, int NB, int N, int E) {
    __shared__ int s[256];
    int tid = threadIdx.x;
    int own = (tid < NB) ? bcnt[tid] : 0;
    s[tid] = own;
    __syncthreads();
    for (int d = 1; d < 256; d <<= 1) {
        int v = (tid >= d) ? s[tid - d] : 0;
        __syncthreads();
        s[tid] += v;
        __syncthreads();
    }
    int excl = s[tid] - own;
    if (tid < NB) { boff[tid] = excl; gcur[tid] = excl; }
    if (tid == 0) {
        boff[NB] = E; rowoff[N] = E;
        int run = 0;
        for (int l = 0; l < NT; ++l) {
            lstart[l] = run;
            run += (lc[l] + 63) & ~63;
        }
    }
}

// ------- node scatter: build iperm (orig -> label-sorted slot) -------
__global__ void scatter_nodes(const int* __restrict__ labels, const int* __restrict__ lstart,
                              int* __restrict__ lcur, int* __restrict__ iperm, int N) {
    int n = blockIdx.x * 256 + threadIdx.x;
    int lab = (n < N) ? labels[n] : -1;
    int lane = threadIdx.x & 63;
    for (int l = 0; l < NT; ++l) {
        unsigned long long m = __ballot(lab == l);
        if (m == 0ull) continue;
        int leader = __builtin_ctzll(m);
        int base = 0;
        if (lane == leader) base = atomicAdd(&lcur[l], (int)__popcll(m));
        base = __shfl(base, leader, 64);
        if (lab == l) {
            int prefix = (int)__popcll(m & ((1ull << lane) - 1ull));
            iperm[n] = lstart[l] + base + prefix;
        }
    }
}

// ================= FUSE_A: scatter_edges + cast_x + cast_w_all =================
// seg 0 [0, nbEB): edge scatter into bucket regions; earr rec: x = slot|(dst&255)<<16, y = w
// seg 1 [nbEB, nbEB+nbX): cast x -> bf16 half-split slot rows
// seg 2 rest: cast W1/W2/W3 -> swizzled bf16 + permuted biases
__global__ __launch_bounds__(512) void fuse_a(
    const int* __restrict__ src, const int* __restrict__ dst, const float* __restrict__ w,
    const int* __restrict__ iperm, int* __restrict__ gcur, uint2* __restrict__ earr, int E,
    const float* __restrict__ x, unsigned short* __restrict__ actLo,
    unsigned short* __restrict__ actHi, int total4,
    const float* __restrict__ W1, const float* __restrict__ W2, const float* __restrict__ W3,
    const float* __restrict__ b1, const float* __restrict__ b2,
    unsigned short* __restrict__ W1b, unsigned short* __restrict__ W2b,
    unsigned short* __restrict__ W3b, float* __restrict__ biasPerm,
    int nbEB, int nbX) {
    int tid = threadIdx.x;
    int blk = (int)blockIdx.x;
    if (blk < nbEB) {
        // ---- edge scatter ----
        __shared__ int h[256];
        __shared__ int basearr[256];
        if (tid < 256) h[tid] = 0;
        __syncthreads();
        int base = blk * 4096;
        int b[8], rank[8], px[8]; float wv[8];
#pragma unroll
        for (int k = 0; k < 8; ++k) {
            int e = base + k * 512 + tid;
            if (e < E) {
                int d = dst[e];
                b[k] = ((unsigned)d) >> 8;
                px[k] = iperm[src[e]] | ((d & 255) << 16);
                wv[k] = w[e];
                rank[k] = atomicAdd(&h[b[k]], 1);
            } else b[k] = -1;
        }
        __syncthreads();
        if (tid < 256) { int c = h[tid]; basearr[tid] = c ? atomicAdd(&gcur[tid], c) : 0; }
        __syncthreads();
#pragma unroll
        for (int k = 0; k < 8; ++k) {
            if (b[k] >= 0) {
                int pos = basearr[b[k]] + rank[k];
                earr[pos] = make_uint2((unsigned)px[k], __float_as_uint(wv[k]));
            }
        }
    } else if (blk < nbEB + nbX) {
        // ---- cast x ----
        int i = (blk - nbEB) * 512 + tid;
        if (i < total4) {
            float4 v = ((const float4*)x)[i];
            unsigned int lo = f2bf_bits(v.x) | (f2bf_bits(v.y) << 16);
            unsigned int hi = f2bf_bits(v.z) | (f2bf_bits(v.w) << 16);
            int slot = iperm[i >> 6];
            unsigned short* dp = ((i & 63) >= 32) ? actHi : actLo;
            ((uint2*)dp)[(size_t)slot * 32 + (i & 31)] = make_uint2(lo, hi);
        }
    } else {
        // ---- cast W + biases ----
        const int S = NT * FEAT * FEAT;
        const int S3 = NT * FEAT * OUT3;
        int idx = (blk - nbEB - nbX) * 512 + tid;
        if (idx < 2 * S + S3) {
            const float* W; unsigned short* D; int OUTF; int t; bool remap;
            if (idx < S)          { W = W1; D = W1b; OUTF = FEAT; t = idx;         remap = false; }
            else if (idx < 2 * S) { W = W2; D = W2b; OUTF = FEAT; t = idx - S;     remap = true; }
            else                  { W = W3; D = W3b; OUTF = OUT3; t = idx - 2 * S; remap = true; }
            int n = t % OUTF;
            int r = t / OUTF;              // lab*256 + k_slot
            int j = r & 7, q = (r >> 3) & 3, k0 = (r >> 5) & 7, lab = r >> 8;
            int k_slot = k0 * 32 + q * 8 + j;
            int k_src = remap ? nat_of(k_slot) : k_slot;
            float f = W[((size_t)(lab * FEAT + k_src)) * OUTF + n];
            D[(((size_t)lab * 8 + k0) * OUTF + n) * 32 + q * 8 + j] = (unsigned short)f2bf_bits(f);
        } else {
            int p2 = idx - (2 * S + S3);
            if (p2 < 256) biasPerm[p2] = b1[nat_of(p2)];
            else if (p2 < 512) biasPerm[p2] = b2[nat_of(p2 - 256)];
        }
    }
}

// ------- bucket sort body (256 thr): within-bucket counting sort -> rowoff + edata -------
// final record: (w_bf16 << 16) | src_slot
__device__ void bucket_sort_body(int b, const uint2* __restrict__ earr,
                                 const int* __restrict__ boff, int* __restrict__ rowoff,
                                 unsigned int* __restrict__ edata, int N) {
    int s = boff[b], e = boff[b + 1];
    __shared__ int cnt[256], off[256];
    int tid = threadIdx.x;
    cnt[tid] = 0;
    __syncthreads();
    for (int i = s + tid; i < e; i += 256) atomicAdd(&cnt[(earr[i].x >> 16) & 255], 1);
    __syncthreads();
    off[tid] = cnt[tid];
    __syncthreads();
    for (int d = 1; d < 256; d <<= 1) {
        int v = (tid >= d) ? off[tid - d] : 0;
        __syncthreads();
        off[tid] += v;
        __syncthreads();
    }
    int excl = off[tid] - cnt[tid];
    int node = b * 256 + tid;
    if (node < N) rowoff[node] = s + excl;
    off[tid] = excl;
    __syncthreads();
    for (int i = s + tid; i < e; i += 256) {
        uint2 r = earr[i];
        int d = (r.x >> 16) & 255;
        int k = atomicAdd(&off[d], 1);
        edata[s + k] = (f2bf_bits(__uint_as_float(r.y)) << 16) | (r.x & 0xffff);
    }
}

// ------- proj 256-out body: dense 64 slots x 256 outs per block, half-split I/O -------
__device__ void proj256_body(int gb,
                             const unsigned short* __restrict__ actLo,
                             const unsigned short* __restrict__ actHi,
                             const unsigned short* __restrict__ Wswz,
                             const int* __restrict__ lstart,
                             unsigned short* __restrict__ supLo,
                             unsigned short* __restrict__ supHi) {
    int warp = threadIdx.x >> 6;
    int lane = threadIdx.x & 63;
    int m0 = gb * 64;
    int lab = (m0 >= lstart[1]) + (m0 >= lstart[2]) + (m0 >= lstart[3]);
    int q = lane >> 4, c = lane & 15;
    int n0 = warp * 64;

    const unsigned short* aLo = actLo + (size_t)(m0 + c) * 128 + q * 8;
    const unsigned short* aHi = actHi + (size_t)(m0 + c) * 128 + q * 8;
    const unsigned short* bb = Wswz + (size_t)lab * FEAT * 256 + (size_t)(n0 + c) * 32 + q * 8;

    f32x4 acc[4][4] = {};
#pragma unroll
    for (int k0 = 0; k0 < 8; ++k0) {
        const unsigned short* abase = (k0 < 4) ? aLo : aHi;
        int koff = (k0 & 3) * 32;
        bf16x8 a[4];
#pragma unroll
        for (int t = 0; t < 4; ++t) a[t] = *(const bf16x8*)(abase + (size_t)t * 2048 + koff);
        const unsigned short* bk = bb + (size_t)k0 * 32 * 256;
#pragma unroll
        for (int u = 0; u < 4; ++u) {
            bf16x8 bfrag = *(const bf16x8*)(bk + u * 512);
#pragma unroll
            for (int t = 0; t < 4; ++t)
                acc[t][u] = __builtin_amdgcn_mfma_f32_16x16x32_bf16(a[t], bfrag, acc[t][u], 0, 0, 0);
        }
    }
    // pi-store: row = m0+t*16+q*4+r ; lane writes p = n0 + c*4 + u -> half n0>>7
    uint2* ov = (uint2*)((n0 >= 128) ? supHi : supLo);
    int cix = ((n0 & 64) >> 2) + c;
#pragma unroll
    for (int t = 0; t < 4; ++t) {
#pragma unroll
        for (int r = 0; r < 4; ++r) {
            int row = m0 + t * 16 + q * 4 + r;
            unsigned int lo = f2bf_bits(acc[t][0][r]) | (f2bf_bits(acc[t][1][r]) << 16);
            unsigned int hi = f2bf_bits(acc[t][2][r]) | (f2bf_bits(acc[t][3][r]) << 16);
            ov[(size_t)row * 32 + cix] = make_uint2(lo, hi);
        }
    }
}

// ================= FUSE_B: bucket_sort (blocks [0,NB)) + proj256 L1 (rest) =================
__global__ __launch_bounds__(256) void fuse_b(
    const uint2* __restrict__ earr, const int* __restrict__ boff,
    int* __restrict__ rowoff, unsigned int* __restrict__ edata, int N, int NB,
    const unsigned short* __restrict__ actLo, const unsigned short* __restrict__ actHi,
    const unsigned short* __restrict__ Wswz, const int* __restrict__ lstart,
    unsigned short* __restrict__ supLo, unsigned short* __restrict__ supHi) {
    int blk = (int)blockIdx.x;
    if (blk < NB) bucket_sort_body(blk, earr, boff, rowoff, edata, N);
    else proj256_body(blk - NB, actLo, actHi, Wswz, lstart, supLo, supHi);
}

// ---------------- standalone proj 256 (layer 2) ----------------
__global__ __launch_bounds__(256) void proj256_kernel(
    const unsigned short* __restrict__ actLo, const unsigned short* __restrict__ actHi,
    const unsigned short* __restrict__ Wswz, const int* __restrict__ lstart,
    unsigned short* __restrict__ supLo, unsigned short* __restrict__ supHi) {
    proj256_body((int)blockIdx.x, actLo, actHi, Wswz, lstart, supLo, supHi);
}

// ---------------- proj 64-out: dense 64 slots x 64 outs per block, half-split input ------
__global__ __launch_bounds__(256) void proj64_kernel(
    const unsigned short* __restrict__ actLo, const unsigned short* __restrict__ actHi,
    const unsigned short* __restrict__ Wswz, const int* __restrict__ lstart,
    unsigned short* __restrict__ outp) {
    int warp = threadIdx.x >> 6;
    int lane = threadIdx.x & 63;
    int m0 = blockIdx.x * 64;
    int lab = (m0 >= lstart[1]) + (m0 >= lstart[2]) + (m0 >= lstart[3]);
    int q = lane >> 4, c = lane & 15;
    int mb = m0 + warp * 16;

    const unsigned short* aLo = actLo + (size_t)(mb + c) * 128 + q * 8;
    const unsigned short* aHi = actHi + (size_t)(mb + c) * 128 + q * 8;
    const unsigned short* bb = Wswz + (size_t)lab * FEAT * OUT3 + (size_t)c * 32 + q * 8;

    f32x4 acc[4] = {};
#pragma unroll
    for (int k0 = 0; k0 < 8; ++k0) {
        const unsigned short* abase = (k0 < 4) ? aLo : aHi;
        bf16x8 a = *(const bf16x8*)(abase + (k0 & 3) * 32);
        const unsigned short* bk = bb + (size_t)k0 * 32 * OUT3;
#pragma unroll
        for (int u = 0; u < 4; ++u) {
            bf16x8 bfrag = *(const bf16x8*)(bk + u * 512);
            acc[u] = __builtin_amdgcn_mfma_f32_16x16x32_bf16(a, bfrag, acc[u], 0, 0, 0);
        }
    }
    uint2* ov = (uint2*)outp;
#pragma unroll
    for (int r = 0; r < 4; ++r) {
        int row = mb + q * 4 + r;
        unsigned int lo = f2bf_bits(acc[0][r]) | (f2bf_bits(acc[1][r]) << 16);
        unsigned int hi = f2bf_bits(acc[2][r]) | (f2bf_bits(acc[3][r]) << 16);
        ov[(size_t)row * 16 + c] = make_uint2(lo, hi);
    }
}

// ------- aggregation over ONE feature half (128 feats): one wave per node, unroll 16 -----
// sup half row = 64 uints (256B). lane handles stored pos p = half*128 + 2*lane, +1.
// Phase-fenced (sched_barrier) so all 16 gathers are in flight before any FMA:
// without the fences the compiler re-rolls to ~3 outstanding loads (VGPR_Count=24).
__global__ __launch_bounds__(256) void agg256h_kernel(
    const unsigned int* __restrict__ sup, const int* __restrict__ rowoff,
    const unsigned int* __restrict__ edata, const int* __restrict__ iperm,
    const float* __restrict__ biasHalf, unsigned int* __restrict__ outp, int N) {
    int warp = __builtin_amdgcn_readfirstlane((int)(threadIdx.x >> 6));
    int node = (int)blockIdx.x * 4 + warp;
    if (node >= N) return;
    int lane = threadIdx.x & 63;
    int s = __builtin_amdgcn_readfirstlane(rowoff[node]);
    int e = __builtin_amdgcn_readfirstlane(rowoff[node + 1]);
    int slot = __builtin_amdgcn_readfirstlane(iperm[node]);
    float a0 = 0.f, a1 = 0.f;
    int j = s;
    for (; j + 16 <= e; j += 16) {
        unsigned int ed[16], v[16];
#pragma unroll
        for (int u = 0; u < 16; ++u) ed[u] = edata[j + u];
        __builtin_amdgcn_sched_barrier(0);
#pragma unroll
        for (int u = 0; u < 16; ++u) v[u] = sup[(size_t)(ed[u] & 0xffff) * 64 + lane];
        __builtin_amdgcn_sched_barrier(0);
#pragma unroll
        for (int u = 0; u < 16; ++u) {
            float w = __uint_as_float(ed[u] & 0xffff0000u);
            a0 += w * bfl(v[u]); a1 += w * bfh(v[u]);
        }
    }
    if (j < e) {   // masked tail (<=15 real edges)
        unsigned int ed[16], v[16]; float wm[16];
#pragma unroll
        for (int u = 0; u < 16; ++u) {
            int jj = j + u;
            int jc = (jj < e) ? jj : e - 1;
            ed[u] = edata[jc];
            wm[u] = (jj < e) ? __uint_as_float(ed[u] & 0xffff0000u) : 0.f;
        }
        __builtin_amdgcn_sched_barrier(0);
#pragma unroll
        for (int u = 0; u < 16; ++u) v[u] = sup[(size_t)(ed[u] & 0xffff) * 64 + lane];
        __builtin_amdgcn_sched_barrier(0);
#pragma unroll
        for (int u = 0; u < 16; ++u) { a0 += wm[u] * bfl(v[u]); a1 += wm[u] * bfh(v[u]); }
    }
    float2 b = ((const float2*)biasHalf)[lane];
    a0 = fmaxf(a0 + b.x, 0.f);
    a1 = fmaxf(a1 + b.y, 0.f);
    unsigned int o = f2bf_bits(a0) | (f2bf_bits(a1) << 16);
    // output rows never re-read here: nontemporal keeps sup lines resident in L2
    __builtin_nontemporal_store(o, &outp[(size_t)slot * 64 + lane]);
}

// ---------------- aggregation, 64-feat: one wave per node (lane = stored pos), fp32 out --
__global__ __launch_bounds__(256) void agg64_kernel(
    const unsigned short* __restrict__ sup, const int* __restrict__ rowoff,
    const unsigned int* __restrict__ edata, const float* __restrict__ b3,
    float* __restrict__ outp, int N) {
    int warp = __builtin_amdgcn_readfirstlane((int)(threadIdx.x >> 6));
    int node = (int)blockIdx.x * 4 + warp;
    if (node >= N) return;
    int lane = threadIdx.x & 63;
    int s = __builtin_amdgcn_readfirstlane(rowoff[node]);
    int e = __builtin_amdgcn_readfirstlane(rowoff[node + 1]);
    float a = 0.f;
    int j = s;
    for (; j + 16 <= e; j += 16) {
        unsigned int ed[16]; unsigned short v[16];
#pragma unroll
        for (int u = 0; u < 16; ++u) ed[u] = edata[j + u];
        __builtin_amdgcn_sched_barrier(0);
#pragma unroll
        for (int u = 0; u < 16; ++u) v[u] = sup[(size_t)(ed[u] & 0xffff) * 64 + lane];
        __builtin_amdgcn_sched_barrier(0);
#pragma unroll
        for (int u = 0; u < 16; ++u)
            a += __uint_as_float(ed[u] & 0xffff0000u) * __uint_as_float((unsigned int)v[u] << 16);
    }
    if (j < e) {
        unsigned int ed[16]; float wm[16]; unsigned short v[16];
#pragma unroll
        for (int u = 0; u < 16; ++u) {
            int jj = j + u;
            int jc = (jj < e) ? jj : e - 1;
            ed[u] = edata[jc];
            wm[u] = (jj < e) ? __uint_as_float(ed[u] & 0xffff0000u) : 0.f;
        }
        __builtin_amdgcn_sched_barrier(0);
#pragma unroll
        for (int u = 0; u < 16; ++u) v[u] = sup[(size_t)(ed[u] & 0xffff) * 64 + lane];
        __builtin_amdgcn_sched_barrier(0);
#pragma unroll
        for (int u = 0; u < 16; ++u)
            a += wm[u] * __uint_as_float((unsigned int)v[u] << 16);
    }
    int natp = (((lane & 3) << 4) | (lane >> 2));    // un-permute pi within the 64 outs
    outp[(size_t)node * 64 + natp] = a + b3[natp];
}

extern "C" void kernel_launch(void* const* d_in, const int* in_sizes, int n_in,
                              void* d_out, int out_size, void* d_ws, size_t ws_size,
                              hipStream_t stream) {
    const float* x        = (const float*)d_in[0];
    const int*   edge_src = (const int*)d_in[1];
    const int*   edge_dst = (const int*)d_in[2];
    const float* edge_w   = (const float*)d_in[3];
    const int*   labels   = (const int*)d_in[4];
    const float* W1 = (const float*)d_in[5];
    const float* b1 = (const float*)d_in[6];
    const float* W2 = (const float*)d_in[7];
    const float* b2 = (const float*)d_in[8];
    const float* W3 = (const float*)d_in[9];
    const float* b3 = (const float*)d_in[10];

    const int N = in_sizes[0] / FEAT;
    const int E = in_sizes[1];
    const int NB = (N + 255) >> 8;                    // dst buckets (orig id space)
    const int G64 = (N + NT * 64 + 63) / 64;          // slot-space 64-row tiles (upper bound)
    const int slotCap = G64 * 64;

    // ---- workspace carve (256B aligned) ----
    char* p = (char*)d_ws;
    auto alloc = [&](size_t bytes) -> char* {
        char* r = p;
        p += (bytes + 255) & ~(size_t)255;
        return r;
    };
    unsigned short* bufA = (unsigned short*)alloc((size_t)slotCap * FEAT * 2);
    unsigned short* bufB = (unsigned short*)alloc((size_t)slotCap * FEAT * 2);
    unsigned short* W1b  = (unsigned short*)alloc((size_t)NT * FEAT * FEAT * 2);
    unsigned short* W2b  = (unsigned short*)alloc((size_t)NT * FEAT * FEAT * 2);
    unsigned short* W3b  = (unsigned short*)alloc((size_t)NT * FEAT * OUT3 * 2);
    float*        biasPerm = (float*)alloc(512 * 4);
    int*          rowoff = (int*)alloc((size_t)(N + 1) * 4);
    unsigned int* edata  = (unsigned int*)alloc((size_t)E * 4);
    int*          iperm  = (int*)alloc((size_t)N * 4);
    int*          counters = (int*)alloc(264 * 4);    // bcnt[256] + lc[4] + lcur[4]
    int*          boff   = (int*)alloc(257 * 4);
    int*          gcur   = (int*)alloc(256 * 4);
    int*          lstart = (int*)alloc(64);
    int* bcnt = counters;
    int* lc   = counters + 256;
    int* lcur = counters + 260;

    // half-table views (lo = feats p<128, hi = p>=128), each slotCap*128 ushorts
    unsigned short* actLo = bufA;
    unsigned short* actHi = bufA + (size_t)slotCap * 128;
    unsigned short* supLo = bufB;
    unsigned short* supHi = bufB + (size_t)slotCap * 128;
    // bucket-sort staging ALIASED onto d_out (N*OUT3*4 = 12.8MB = E*8; d_out written
    // only by the final agg64, and earr is fully overwritten by scatter before reads)
    uint2* earr = (uint2*)d_out;

    const int nbEB = (E + 4095) / 4096;
    const int total4 = N * 64;                        // float4 groups in x
    const int nbX = (total4 + 511) / 512;
    const int totW = 2 * NT * FEAT * FEAT + NT * FEAT * OUT3 + 512;
    const int nbW = (totW + 511) / 512;

    // ---- CSR build + label-sort + casts ----
    hipMemsetAsync(counters, 0, 264 * 4, stream);
    pass_a<<<nbEB, 512, 0, stream>>>(edge_dst, labels, bcnt, lc, E, N);
    scan_master<<<1, 256, 0, stream>>>(bcnt, lc, boff, gcur, rowoff, lstart, NB, N, E);
    scatter_nodes<<<(N + 255) / 256, 256, 0, stream>>>(labels, lstart, lcur, iperm, N);
    fuse_a<<<nbEB + nbX + nbW, 512, 0, stream>>>(
        edge_src, edge_dst, edge_w, iperm, gcur, earr, E,
        x, actLo, actHi, total4,
        W1, W2, W3, b1, b2, W1b, W2b, W3b, biasPerm, nbEB, nbX);

    const int aggGrid = (N + 3) / 4;
    // ---- layer 1 (bucket_sort overlapped with proj256-L1) ----
    fuse_b<<<NB + G64, 256, 0, stream>>>(earr, boff, rowoff, edata, N, NB,
                                         actLo, actHi, W1b, lstart, supLo, supHi);
    agg256h_kernel<<<aggGrid, 256, 0, stream>>>((const unsigned int*)supLo, rowoff, edata, iperm,
                                                biasPerm + 0, (unsigned int*)actLo, N);
    agg256h_kernel<<<aggGrid, 256, 0, stream>>>((const unsigned int*)supHi, rowoff, edata, iperm,
                                                biasPerm + 128, (unsigned int*)actHi, N);
    // ---- layer 2 ----
    proj256_kernel<<<G64, 256, 0, stream>>>(actLo, actHi, W2b, lstart, supLo, supHi);
    agg256h_kernel<<<aggGrid, 256, 0, stream>>>((const unsigned int*)supLo, rowoff, edata, iperm,
                                                biasPerm + 256, (unsigned int*)actLo, N);
    agg256h_kernel<<<aggGrid, 256, 0, stream>>>((const unsigned int*)supHi, rowoff, edata, iperm,
                                                biasPerm + 384, (unsigned int*)actHi, N);
    // ---- layer 3 ----
    proj64_kernel<<<G64, 256, 0, stream>>>(actLo, actHi, W3b, lstart, bufB);
    agg64_kernel<<<aggGrid, 256, 0, stream>>>(bufB, rowoff, edata, b3, (float*)d_out, N);
}